// Round 9
// baseline (294.908 us; speedup 1.0000x reference)
//
#include <hip/hip_runtime.h>

constexpr int NN    = 128;
constexpr int BB    = 2;
constexpr int DIN   = 128;
constexpr int DD    = 256;
constexpr int DFF   = 1024;
constexpr int NH    = 8;
constexpr int DH    = 32;
constexpr int NL    = 2;
constexpr int BLK   = 32;
constexpr int WMAX  = 2 * BLK + 1;       // 65
constexpr int RROWS = NN * WMAX * BB;    // 16640

typedef __attribute__((ext_vector_type(8))) short s16x8;   // 8 bf16 (4 VGPR)
typedef __attribute__((ext_vector_type(4))) float f32x4;

__device__ __forceinline__ ushort f2bf(float f) {
  unsigned u = __float_as_uint(f);
  unsigned r = (u + 0x7fffu + ((u >> 16) & 1u)) >> 16;    // RNE
  return (ushort)r;
}
__device__ __forceinline__ float bf2f(ushort h) {
  return __uint_as_float(((unsigned)h) << 16);
}

// async global->LDS, 16B per lane; LDS dest must be lane-linear.
__device__ __forceinline__ void gld16(const void* g, void* l) {
  __builtin_amdgcn_global_load_lds(
      (const __attribute__((address_space(1))) void*)g,
      (__attribute__((address_space(3))) void*)l, 16, 0, 0);
}
// vmcnt(0) BEFORE any barrier that publishes global_load_lds data (T3/T4).
__device__ __forceinline__ void vmdrain() {
  asm volatile("s_waitcnt vmcnt(0)" ::: "memory");
}

// ---------------------------------------------------------------------------
// Fused prep: weight transpose tiles + buildx + kp.
// ---------------------------------------------------------------------------
struct TD { const float* in; ushort* out; int K; int N; };
struct TPack { TD d[10]; };
constexpr int WCONV_TILES = 1920;
constexpr int BX_BLOCKS   = RROWS * DIN / 256;   // 8320

__global__ __launch_bounds__(256) void k_prep(
    TPack p, const float* __restrict__ inp, ushort* __restrict__ x,
    const float* __restrict__ kW1, const float* __restrict__ kb1,
    const float* __restrict__ kW2, const float* __restrict__ kb2,
    float* __restrict__ kp) {
  __shared__ float ls[32 * 33];
  int bid = blockIdx.x;
  int tid = threadIdx.x;
  if (bid < WCONV_TILES) {
    const int cum[11] = {0, 128, 384, 576, 768, 832, 896, 1152, 1408, 1664, 1920};
    int mi = 0;
#pragma unroll
    for (int i = 0; i < 10; ++i) if (bid >= cum[i + 1]) mi = i + 1;
    TD t = p.d[mi];
    int tile = bid - cum[mi];
    int ntk = t.K >> 5;
    int tn = tile / ntk, tk = tile - tn * ntk;
    int r = tid >> 5, c = tid & 31;
#pragma unroll
    for (int i = 0; i < 4; ++i) {
      int kk = r + 8 * i;
      ls[kk * 33 + c] = t.in[(size_t)(tk * 32 + kk) * t.N + tn * 32 + c];
    }
    __syncthreads();
#pragma unroll
    for (int i = 0; i < 4; ++i) {
      int rr = r + 8 * i;
      t.out[(size_t)(tn * 32 + rr) * t.K + tk * 32 + c] = f2bf(ls[c * 33 + rr]);
    }
  } else if (bid < WCONV_TILES + BX_BLOCKS) {
    int e = (bid - WCONV_TILES) * 256 + tid;       // < R*128
    int i = e & 127, r = e >> 7;
    int n = r / (WMAX * BB);
    int rem = r - n * (WMAX * BB);
    int w = rem >> 1, b = rem & 1;
    int st = n - BLK; if (st < 0) st = 0;
    float pos = (float)(st + w);
    float div = __expf(-0.0719557841f * (float)(i & 126));
    float ang = pos * div;
    float pe = (i & 1) ? __cosf(ang) : __sinf(ang);
    x[e] = f2bf(inp[(n * BB + b) * DIN + i] + pe);
  } else {
    int row = bid - (WCONV_TILES + BX_BLOCKS);
    float* xs = ls;
    float* red = ls + 256;
    if (tid < DIN) xs[tid] = inp[row * DIN + tid];
    __syncthreads();
    float a0 = 0.f, a1 = 0.f;
    for (int j = tid; j < DFF; j += 256) {
      float acc = kb1[j];
      for (int k = 0; k < DIN; ++k) acc += xs[k] * kW1[k * DFF + j];
      acc = fmaxf(acc, 0.f);
      a0 += acc * kW2[2 * j];
      a1 += acc * kW2[2 * j + 1];
    }
#pragma unroll
    for (int m = 32; m > 0; m >>= 1) {
      a0 += __shfl_xor(a0, m, 64);
      a1 += __shfl_xor(a1, m, 64);
    }
    if ((tid & 63) == 0) { red[(tid >> 6) * 2] = a0; red[(tid >> 6) * 2 + 1] = a1; }
    __syncthreads();
    if (tid == 0) {
      kp[row * 2 + 0] = red[0] + red[2] + red[4] + red[6] + kb2[0];
      kp[row * 2 + 1] = red[1] + red[3] + red[5] + red[7] + kb2[1];
    }
  }
}

// ---------------------------------------------------------------------------
// 8-wave MFMA GEMM (qkv projection), BN=256, gld16 staging.
// ---------------------------------------------------------------------------
template<int BMT>
__global__ __launch_bounds__(512) void k_gemm8(
    const ushort* __restrict__ A, const ushort* __restrict__ Bt,
    const float* __restrict__ bias, ushort* __restrict__ out, int N, int K) {
  constexpr int MF = BMT / 32;
  __shared__ __align__(16) char As[BMT * 128];
  __shared__ __align__(16) char Bs[256 * 128];
  int tid = threadIdx.x;
  int m0 = blockIdx.x * BMT, n0 = blockIdx.y * 256;
  int lane = tid & 63, w = tid >> 6;
  int wr = w >> 2, wc = w & 3;
  int fr = lane & 15, g = lane >> 4;
  f32x4 acc[MF][4] = {};

  for (int kb = 0; kb < K; kb += 64) {
    __syncthreads();
#pragma unroll
    for (int it = 0; it < BMT / 64; ++it) {
      int e = tid + it * 512;
      int row = e >> 3, c = e & 7;
      gld16(A + (size_t)(m0 + row) * K + kb + ((c ^ (row & 7)) * 8), As + e * 16);
    }
#pragma unroll
    for (int it = 0; it < 4; ++it) {
      int e = tid + it * 512;
      int row = e >> 3, c = e & 7;
      gld16(Bt + (size_t)(n0 + row) * K + kb + ((c ^ (row & 7)) * 8), Bs + e * 16);
    }
    vmdrain();
    __syncthreads();
#pragma unroll
    for (int ks = 0; ks < 2; ++ks) {
      int kByte = ks * 64 + g * 16;
      s16x8 a[MF], b[4];
#pragma unroll
      for (int m = 0; m < MF; ++m) {
        int row = wr * (BMT / 2) + m * 16 + fr;
        a[m] = *(const s16x8*)(As + ((row * 128 + kByte) ^ ((row & 7) << 4)));
      }
#pragma unroll
      for (int n = 0; n < 4; ++n) {
        int row = wc * 64 + n * 16 + fr;
        b[n] = *(const s16x8*)(Bs + ((row * 128 + kByte) ^ ((row & 7) << 4)));
      }
#pragma unroll
      for (int m = 0; m < MF; ++m)
#pragma unroll
        for (int n = 0; n < 4; ++n)
          acc[m][n] = __builtin_amdgcn_mfma_f32_16x16x32_bf16(a[m], b[n], acc[m][n], 0, 0, 0);
    }
  }
#pragma unroll
  for (int m = 0; m < MF; ++m) {
    int rowb = m0 + wr * (BMT / 2) + m * 16 + g * 4;
#pragma unroll
    for (int n = 0; n < 4; ++n) {
      int col = n0 + wc * 64 + n * 16 + fr;
      float bv = bias[col];
#pragma unroll
      for (int j = 0; j < 4; ++j)
        out[(size_t)(rowb + j) * N + col] = f2bf(acc[m][n][j] + bv);
    }
  }
}

// ---------------------------------------------------------------------------
// Fused input MLP: hb = relu(x @ inW1 + b1) @ inW2 + b2.
// 64-row blocks; t stays in LDS; weights streamed in 16 chunks of 64 cols.
// ---------------------------------------------------------------------------
__global__ __launch_bounds__(512) void k_inmlp(
    const ushort* __restrict__ x, const ushort* __restrict__ W1t,
    const float* __restrict__ b1, const ushort* __restrict__ W2t,
    const float* __restrict__ b2, ushort* __restrict__ hb) {
  __shared__ __align__(16) char lds[73728];
  char* xs  = lds;            // 16 KB: 2 K-slabs of 64 rows x 128B
  char* ts  = lds + 16384;    // 8 KB
  char* w1b = lds + 24576;    // 16 KB: 2 slabs
  char* w2b = lds + 40960;    // 32 KB
  int tid = threadIdx.x;
  int m0 = blockIdx.x * 64;
  int lane = tid & 63, w = tid >> 6;
  int wr = w >> 2, wc = w & 3;
  int fr = lane & 15, g = lane >> 4;

  auto stW1 = [&](int c) {
    int e = tid;
#pragma unroll
    for (int it = 0; it < 2; ++it, e += 512) {
      int kt = e >> 9, row = (e >> 3) & 63, c8 = e & 7;
      gld16(W1t + (size_t)(c * 64 + row) * 128 + kt * 64 + ((c8 ^ (row & 7)) * 8),
            w1b + e * 16);
    }
  };
  auto stW2 = [&](int c) {
    int e = tid;
#pragma unroll
    for (int it = 0; it < 4; ++it, e += 512) {
      int row = e >> 3, c8 = e & 7;
      gld16(W2t + (size_t)row * 1024 + c * 64 + ((c8 ^ (row & 7)) * 8), w2b + e * 16);
    }
  };
  // stage x (64 rows x 128 k)
  {
    int e = tid;
#pragma unroll
    for (int it = 0; it < 2; ++it, e += 512) {
      int kt = e >> 9, row = (e >> 3) & 63, c8 = e & 7;
      gld16(x + (size_t)(m0 + row) * 128 + kt * 64 + ((c8 ^ (row & 7)) * 8), xs + e * 16);
    }
  }
  stW1(0);
  vmdrain();
  __syncthreads();

  f32x4 acc2[2][4] = {};
  for (int c = 0; c < 16; ++c) {
    stW2(c);
    // GEMM1: t = x @ W1c  (M=64,N=64,K=128); wave grid 2x4 -> tile 32x16
    f32x4 t1[2] = {};
#pragma unroll
    for (int kt = 0; kt < 2; ++kt)
#pragma unroll
      for (int ks = 0; ks < 2; ++ks) {
        int kByte = ks * 64 + g * 16;
        int brow = wc * 16 + fr;
        s16x8 bfrag = *(const s16x8*)(w1b + kt * 8192 +
                        ((brow * 128 + kByte) ^ ((brow & 7) << 4)));
#pragma unroll
        for (int m = 0; m < 2; ++m) {
          int row = wr * 32 + m * 16 + fr;
          s16x8 afrag = *(const s16x8*)(xs + kt * 8192 +
                          ((row * 128 + kByte) ^ ((row & 7) << 4)));
          t1[m] = __builtin_amdgcn_mfma_f32_16x16x32_bf16(afrag, bfrag, t1[m], 0, 0, 0);
        }
      }
    vmdrain();       // W2[c] landed
    __syncthreads(); // GEMM1 done everywhere; ts/w1b free
    {
      int col = wc * 16 + fr;
      float bv = b1[c * 64 + col];
#pragma unroll
      for (int m = 0; m < 2; ++m) {
        int rowb = wr * 32 + m * 16 + g * 4;
#pragma unroll
        for (int j = 0; j < 4; ++j) {
          int r = rowb + j;
          *(ushort*)(ts + ((r * 128 + col * 2) ^ ((r & 7) << 4))) =
              f2bf(fmaxf(t1[m][j] + bv, 0.f));
        }
      }
    }
    if (c < 15) stW1(c + 1);
    __syncthreads(); // ts visible
    // GEMM2: acc2 += t @ W2c  (K=64)
#pragma unroll
    for (int ks = 0; ks < 2; ++ks) {
      int kByte = ks * 64 + g * 16;
      s16x8 afrag[2];
#pragma unroll
      for (int m = 0; m < 2; ++m) {
        int row = wr * 32 + m * 16 + fr;
        afrag[m] = *(const s16x8*)(ts + ((row * 128 + kByte) ^ ((row & 7) << 4)));
      }
#pragma unroll
      for (int n = 0; n < 4; ++n) {
        int row = wc * 64 + n * 16 + fr;
        s16x8 bfrag = *(const s16x8*)(w2b + ((row * 128 + kByte) ^ ((row & 7) << 4)));
#pragma unroll
        for (int m = 0; m < 2; ++m)
          acc2[m][n] = __builtin_amdgcn_mfma_f32_16x16x32_bf16(afrag[m], bfrag, acc2[m][n], 0, 0, 0);
      }
    }
    vmdrain();       // W1[c+1] landed
    __syncthreads(); // w2b free for next chunk
  }
#pragma unroll
  for (int m = 0; m < 2; ++m) {
    int rowb = m0 + wr * 32 + m * 16 + g * 4;
#pragma unroll
    for (int n = 0; n < 4; ++n) {
      int col = wc * 64 + n * 16 + fr;
      float bv = b2[col];
#pragma unroll
      for (int j = 0; j < 4; ++j)
        hb[(size_t)(rowb + j) * 256 + col] = f2bf(acc2[m][n][j] + bv);
    }
  }
}

// ---------------------------------------------------------------------------
// Fused transformer layer tail: h = LN2(h1 + FFN(h1)), h1 = LN1(hb + o@Wo+bo).
// One block = 64 rows. h1 and t live in LDS; weights streamed in chunks.
// ---------------------------------------------------------------------------
__global__ __launch_bounds__(512) void k_layer(
    const ushort* __restrict__ ob, const ushort* __restrict__ Wot,
    const float* __restrict__ bo, const float* __restrict__ ln1g,
    const float* __restrict__ ln1b, const ushort* __restrict__ W1t,
    const float* __restrict__ b1, const ushort* __restrict__ W2t,
    const float* __restrict__ b2, const float* __restrict__ ln2g,
    const float* __restrict__ ln2b, ushort* __restrict__ hb) {
  __shared__ __align__(16) char lds[108544];
  char* h1s = lds;            // 32 KB: 4 slabs; oproj A dbuf in halves 0/8192
  char* ts  = lds + 32768;    // 8 KB
  char* w1b = lds + 40960;    // 32 KB (4 slabs)
  char* w2b = lds + 73728;    // 32 KB
  float* psum = (float*)(lds + 106496);        // [4][64]
  float* psq  = (float*)(lds + 106496 + 1024); // [4][64]
  int tid = threadIdx.x;
  int m0 = blockIdx.x * 64;
  int lane = tid & 63, w = tid >> 6;
  int wr = w >> 2, wc = w & 3;
  int fr = lane & 15, g = lane >> 4;

  // ---- Phase A: oproj acc1 = ob @ Wot^T (M=64,N=256,K=256), dbuf ----
  auto stOA = [&](int half, int t) {
    int e = tid;                 // 512 slots = 8 KB
    int row = e >> 3, c8 = e & 7;
    gld16(ob + (size_t)(m0 + row) * 256 + t * 64 + ((c8 ^ (row & 7)) * 8),
          h1s + half * 8192 + e * 16);
  };
  auto stOB = [&](char* buf, int t) {
    int e = tid;
#pragma unroll
    for (int it = 0; it < 4; ++it, e += 512) {
      int row = e >> 3, c8 = e & 7;
      gld16(Wot + (size_t)row * 256 + t * 64 + ((c8 ^ (row & 7)) * 8), buf + e * 16);
    }
  };
  f32x4 acc1[2][4] = {};
  stOA(0, 0); stOB(w1b, 0);
  vmdrain();
  __syncthreads();
  for (int t = 0; t < 4; ++t) {
    if (t < 3) { stOA((t + 1) & 1, t + 1); stOB((t & 1) ? w1b : w2b, t + 1); }
    const char* Ah = h1s + (t & 1) * 8192;
    const char* Bh = (t & 1) ? w2b : w1b;
#pragma unroll
    for (int ks = 0; ks < 2; ++ks) {
      int kByte = ks * 64 + g * 16;
      s16x8 a[2];
#pragma unroll
      for (int m = 0; m < 2; ++m) {
        int row = wr * 32 + m * 16 + fr;
        a[m] = *(const s16x8*)(Ah + ((row * 128 + kByte) ^ ((row & 7) << 4)));
      }
#pragma unroll
      for (int n = 0; n < 4; ++n) {
        int row = wc * 64 + n * 16 + fr;
        s16x8 b = *(const s16x8*)(Bh + ((row * 128 + kByte) ^ ((row & 7) << 4)));
#pragma unroll
        for (int m = 0; m < 2; ++m)
          acc1[m][n] = __builtin_amdgcn_mfma_f32_16x16x32_bf16(a[m], b, acc1[m][n], 0, 0, 0);
      }
    }
    vmdrain();
    __syncthreads();
  }

  // ---- FFN weight prefetch (chunk 0 W1) overlaps LN1 ----
  auto stW1 = [&](int c) {
    int e = tid;
#pragma unroll
    for (int it = 0; it < 4; ++it, e += 512) {
      int kt = e >> 9, row = (e >> 3) & 63, c8 = e & 7;
      gld16(W1t + (size_t)(c * 64 + row) * 256 + kt * 64 + ((c8 ^ (row & 7)) * 8),
            w1b + e * 16);
    }
  };
  auto stW2 = [&](int c) {
    int e = tid;
#pragma unroll
    for (int it = 0; it < 4; ++it, e += 512) {
      int row = e >> 3, c8 = e & 7;
      gld16(W2t + (size_t)row * 1024 + c * 64 + ((c8 ^ (row & 7)) * 8), w2b + e * 16);
    }
  };
  stW1(0);

  // ---- LN1: z1 = acc1 + bo + hb(resid); h1 -> LDS slabs ----
#pragma unroll
  for (int m = 0; m < 2; ++m) {
    int rowb = wr * 32 + m * 16 + g * 4;
#pragma unroll
    for (int j = 0; j < 4; ++j) {
      int r = rowb + j;
      float ps = 0.f, pq = 0.f;
#pragma unroll
      for (int n = 0; n < 4; ++n) {
        int col = wc * 64 + n * 16 + fr;
        float v = acc1[m][n][j] + bo[col] + bf2f(hb[(size_t)(m0 + r) * 256 + col]);
        acc1[m][n][j] = v;
        ps += v; pq += v * v;
      }
#pragma unroll
      for (int d = 1; d < 16; d <<= 1) {
        ps += __shfl_xor(ps, d, 64);
        pq += __shfl_xor(pq, d, 64);
      }
      if (fr == 0) { psum[wc * 64 + r] = ps; psq[wc * 64 + r] = pq; }
    }
  }
  __syncthreads();
#pragma unroll
  for (int m = 0; m < 2; ++m) {
    int rowb = wr * 32 + m * 16 + g * 4;
#pragma unroll
    for (int j = 0; j < 4; ++j) {
      int r = rowb + j;
      float sm = psum[r] + psum[64 + r] + psum[128 + r] + psum[192 + r];
      float sq = psq[r] + psq[64 + r] + psq[128 + r] + psq[192 + r];
      float mean = sm * (1.f / 256.f);
      float var = sq * (1.f / 256.f) - mean * mean;
      float rs = rsqrtf(var + 1e-5f);
#pragma unroll
      for (int n = 0; n < 4; ++n) {
        int col = wc * 64 + n * 16 + fr;
        float v = (acc1[m][n][j] - mean) * rs * ln1g[col] + ln1b[col];
        *(ushort*)(h1s + wc * 8192 + ((r * 128 + (col & 63) * 2) ^ ((r & 7) << 4))) = f2bf(v);
      }
    }
  }
  vmdrain();       // W1[0] landed
  __syncthreads(); // h1 slabs visible

  // ---- FFN chunks: t=relu(h1@W1c+b1c); acc2 += t@W2c ----
  f32x4 acc2[2][4] = {};
  for (int c = 0; c < 16; ++c) {
    stW2(c);
    f32x4 t1[2] = {};
#pragma unroll
    for (int kt = 0; kt < 4; ++kt)
#pragma unroll
      for (int ks = 0; ks < 2; ++ks) {
        int kByte = ks * 64 + g * 16;
        int brow = wc * 16 + fr;
        s16x8 bfrag = *(const s16x8*)(w1b + kt * 8192 +
                        ((brow * 128 + kByte) ^ ((brow & 7) << 4)));
#pragma unroll
        for (int m = 0; m < 2; ++m) {
          int row = wr * 32 + m * 16 + fr;
          s16x8 afrag = *(const s16x8*)(h1s + kt * 8192 +
                          ((row * 128 + kByte) ^ ((row & 7) << 4)));
          t1[m] = __builtin_amdgcn_mfma_f32_16x16x32_bf16(afrag, bfrag, t1[m], 0, 0, 0);
        }
      }
    vmdrain();
    __syncthreads();
    {
      int col = wc * 16 + fr;
      float bv = b1[c * 64 + col];
#pragma unroll
      for (int m = 0; m < 2; ++m) {
        int rowb = wr * 32 + m * 16 + g * 4;
#pragma unroll
        for (int j = 0; j < 4; ++j) {
          int r = rowb + j;
          *(ushort*)(ts + ((r * 128 + col * 2) ^ ((r & 7) << 4))) =
              f2bf(fmaxf(t1[m][j] + bv, 0.f));
        }
      }
    }
    if (c < 15) stW1(c + 1);
    __syncthreads();
#pragma unroll
    for (int ks = 0; ks < 2; ++ks) {
      int kByte = ks * 64 + g * 16;
      s16x8 afrag[2];
#pragma unroll
      for (int m = 0; m < 2; ++m) {
        int row = wr * 32 + m * 16 + fr;
        afrag[m] = *(const s16x8*)(ts + ((row * 128 + kByte) ^ ((row & 7) << 4)));
      }
#pragma unroll
      for (int n = 0; n < 4; ++n) {
        int row = wc * 64 + n * 16 + fr;
        s16x8 bfrag = *(const s16x8*)(w2b + ((row * 128 + kByte) ^ ((row & 7) << 4)));
#pragma unroll
        for (int m = 0; m < 2; ++m)
          acc2[m][n] = __builtin_amdgcn_mfma_f32_16x16x32_bf16(afrag[m], bfrag, acc2[m][n], 0, 0, 0);
      }
    }
    vmdrain();
    __syncthreads();
  }

  // ---- LN2: z2 = acc2 + b2 + h1; write hb ----
#pragma unroll
  for (int m = 0; m < 2; ++m) {
    int rowb = wr * 32 + m * 16 + g * 4;
#pragma unroll
    for (int j = 0; j < 4; ++j) {
      int r = rowb + j;
      float ps = 0.f, pq = 0.f;
#pragma unroll
      for (int n = 0; n < 4; ++n) {
        int col = wc * 64 + n * 16 + fr;
        float h1v = bf2f(*(const ushort*)(h1s + wc * 8192 +
                       ((r * 128 + (col & 63) * 2) ^ ((r & 7) << 4))));
        float v = acc2[m][n][j] + b2[col] + h1v;
        acc2[m][n][j] = v;
        ps += v; pq += v * v;
      }
#pragma unroll
      for (int d = 1; d < 16; d <<= 1) {
        ps += __shfl_xor(ps, d, 64);
        pq += __shfl_xor(pq, d, 64);
      }
      if (fr == 0) { psum[wc * 64 + r] = ps; psq[wc * 64 + r] = pq; }
    }
  }
  __syncthreads();
#pragma unroll
  for (int m = 0; m < 2; ++m) {
    int rowb = wr * 32 + m * 16 + g * 4;
#pragma unroll
    for (int j = 0; j < 4; ++j) {
      int r = rowb + j;
      float sm = psum[r] + psum[64 + r] + psum[128 + r] + psum[192 + r];
      float sq = psq[r] + psq[64 + r] + psq[128 + r] + psq[192 + r];
      float mean = sm * (1.f / 256.f);
      float var = sq * (1.f / 256.f) - mean * mean;
      float rs = rsqrtf(var + 1e-5f);
#pragma unroll
      for (int n = 0; n < 4; ++n) {
        int col = wc * 64 + n * 16 + fr;
        float v = (acc2[m][n][j] - mean) * rs * ln2g[col] + ln2b[col];
        hb[(size_t)(m0 + r) * 256 + col] = f2bf(v);
      }
    }
  }
}

// ---------------------------------------------------------------------------
// MFMA windowed attention (unchanged from round 8).
// ---------------------------------------------------------------------------
constexpr int QKS = 40;
constexpr int VTS = 104;
constexpr int PS  = 104;

__device__ __forceinline__ int vslot(int d, int r) {
  int rc = r >> 3;
  int sw = (rc < 8) ? (rc ^ (d >> 3)) : rc;
  return d * VTS + sw * 8 + (r & 7);
}

__global__ __launch_bounds__(320) void k_attn(
    const ushort* __restrict__ qkv, ushort* __restrict__ o,
    const int* __restrict__ lenp) {
  __shared__ __align__(16) ushort Ks[80 * QKS];
  __shared__ __align__(16) ushort Vt[32 * VTS];
  __shared__ __align__(16) ushort Pb[5 * 16 * PS];
  int L = lenp[0];
  int blk = blockIdx.x;
  int hh = blk & 7;
  int nb = blk >> 3;
  int b = nb & 1;
  int n = nb >> 1;
  int s0 = n - BLK; if (s0 < 0) s0 = 0;
  int e0 = n + BLK + 1; if (e0 > L) e0 = L;
  int vn = e0 - s0;
  int tid = threadIdx.x;

  for (int i = tid; i < 32 * VTS / 2; i += 320) ((uint*)Vt)[i] = 0;
  for (int i = tid; i < 15 * QKS / 2; i += 320)
    ((uint*)(Ks + 65 * QKS))[i] = 0;
  __syncthreads();   // zero-fill and staging overlap in Vt: must be ordered
  for (int e = tid; e < 65 * 4; e += 320) {
    int r = e >> 2, c = e & 3;
    const ushort* base = qkv + ((size_t)(n * WMAX + r) * BB + b) * (3 * DD) + hh * DH;
    *(uint4*)(Ks + r * QKS + c * 8) = *(const uint4*)(base + DD + c * 8);
    uint4 vv = *(const uint4*)(base + 2 * DD + c * 8);
    const ushort* vp = (const ushort*)&vv;
#pragma unroll
    for (int u = 0; u < 8; ++u) Vt[vslot(c * 8 + u, r)] = vp[u];
  }

  int w = tid >> 6, lane = tid & 63;
  int fr = lane & 15, g = lane >> 4;
  int q0 = w * 16;
  ushort* Pw = Pb + w * 16 * PS;

  int qr_ld = q0 + fr; if (qr_ld > 64) qr_ld = 64;
  s16x8 aq = *(const s16x8*)(qkv + ((size_t)(n * WMAX + qr_ld) * BB + b) * (3 * DD)
                             + hh * DH + g * 8);
  __syncthreads();

  f32x4 sacc[5];
#pragma unroll
  for (int t = 0; t < 5; ++t) {
    s16x8 bk = *(const s16x8*)(Ks + (t * 16 + fr) * QKS + g * 8);
    f32x4 z = {0.f, 0.f, 0.f, 0.f};
    sacc[t] = __builtin_amdgcn_mfma_f32_16x16x32_bf16(aq, bk, z, 0, 0, 0);
  }
  const float scl = 0.17677669529663687f;
#pragma unroll
  for (int j = 0; j < 4; ++j) {
    float pv[5];
    float mx = -3e38f;
#pragma unroll
    for (int t = 0; t < 5; ++t) {
      bool ok = (t * 16 + fr) < vn;
      pv[t] = ok ? sacc[t][j] * scl : -3e38f;
      mx = fmaxf(mx, pv[t]);
    }
#pragma unroll
    for (int d = 1; d < 16; d <<= 1) mx = fmaxf(mx, __shfl_xor(mx, d, 64));
    float sum = 0.f;
#pragma unroll
    for (int t = 0; t < 5; ++t) {
      float e = ((t * 16 + fr) < vn) ? __expf(pv[t] - mx) : 0.f;
      pv[t] = e;
      sum += e;
    }
#pragma unroll
    for (int d = 1; d < 16; d <<= 1) sum += __shfl_xor(sum, d, 64);
    float inv = 1.f / sum;
#pragma unroll
    for (int t = 0; t < 5; ++t)
      Pw[(g * 4 + j) * PS + t * 16 + fr] = f2bf(pv[t] * inv);
  }
  {
    int zr = lane >> 2, zc = 80 + (lane & 3) * 4;
    *(uint2*)(Pw + zr * PS + zc) = make_uint2(0u, 0u);
  }
  __syncthreads();

  f32x4 oacc[2] = {};
#pragma unroll
  for (int k0 = 0; k0 < 3; ++k0) {
    s16x8 ap = *(const s16x8*)(Pw + fr * PS + k0 * 32 + g * 8);
#pragma unroll
    for (int nt = 0; nt < 2; ++nt) {
      s16x8 bv = *(const s16x8*)(Vt + vslot(nt * 16 + fr, k0 * 32 + g * 8));
      oacc[nt] = __builtin_amdgcn_mfma_f32_16x16x32_bf16(ap, bv, oacc[nt], 0, 0, 0);
    }
  }
#pragma unroll
  for (int nt = 0; nt < 2; ++nt) {
#pragma unroll
    for (int j = 0; j < 4; ++j) {
      int qr = q0 + g * 4 + j;
      if (qr < WMAX)
        o[((size_t)(n * WMAX + qr) * BB + b) * DD + hh * DH + nt * 16 + fr] =
            f2bf(oacc[nt][j]);
    }
  }
}

// ---------------------------------------------------------------------------
// Final hierarchical softmax-gather (h bf16)
// ---------------------------------------------------------------------------
__global__ __launch_bounds__(256) void k_final(
    const ushort* __restrict__ h, const float* __restrict__ kp,
    float* __restrict__ out, const int* __restrict__ lenp) {
  int L = lenp[0];
  int t = blockIdx.x >> 1, b = blockIdx.x & 1;
  float hsc = (float)L / (float)NN;
  int nlo = t - BLK; if (nlo < 0) nlo = 0;
  int nhi = t + BLK; if (nhi > NN - 1) nhi = NN - 1;
  float mx = -3e38f;
  for (int n = nlo; n <= nhi; ++n) {
    float kp0 = kp[(n * BB + b) * 2 + 0];
    float kp1 = kp[(n * BB + b) * 2 + 1];
    float dif = (float)t - (float)n * hsc - kp0;
    float lg = -dif * dif * __expf(kp1);
    mx = fmaxf(mx, lg);
  }
  float sum = 0.f, acc = 0.f;
  int c = threadIdx.x;
  for (int n = nlo; n <= nhi; ++n) {
    float kp0 = kp[(n * BB + b) * 2 + 0];
    float kp1 = kp[(n * BB + b) * 2 + 1];
    float dif = (float)t - (float)n * hsc - kp0;
    float lg = -dif * dif * __expf(kp1);
    float p = __expf(lg - mx);
    sum += p;
    int st = n - BLK; if (st < 0) st = 0;
    int w = t - st;
    acc += p * bf2f(h[(size_t)((n * WMAX + w) * BB + b) * DD + c]);
  }
  out[(size_t)(t * BB + b) * DD + c] = acc / sum;
}

// ---------------------------------------------------------------------------
extern "C" void kernel_launch(void* const* d_in, const int* in_sizes, int n_in,
                              void* d_out, int out_size, void* d_ws, size_t ws_size,
                              hipStream_t stream) {
  const float* inputs = (const float*)d_in[0];
  const float* in_W1  = (const float*)d_in[1];
  const float* in_b1  = (const float*)d_in[2];
  const float* in_W2  = (const float*)d_in[3];
  const float* in_b2  = (const float*)d_in[4];
  const float* k_W1   = (const float*)d_in[5];
  const float* k_b1   = (const float*)d_in[6];
  const float* k_W2   = (const float*)d_in[7];
  const float* k_b2   = (const float*)d_in[8];
  const float* Wqkv   = (const float*)d_in[9];
  const float* bqkv   = (const float*)d_in[10];
  const float* Wo     = (const float*)d_in[11];
  const float* bo     = (const float*)d_in[12];
  const float* ln1_g  = (const float*)d_in[13];
  const float* ln1_b  = (const float*)d_in[14];
  const float* W1     = (const float*)d_in[15];
  const float* b1     = (const float*)d_in[16];
  const float* W2     = (const float*)d_in[17];
  const float* b2     = (const float*)d_in[18];
  const float* ln2_g  = (const float*)d_in[19];
  const float* ln2_b  = (const float*)d_in[20];
  const int*   lenp   = (const int*)d_in[21];
  float* out = (float*)d_out;
  (void)in_sizes; (void)n_in; (void)ws_size;

  ushort* wsu = (ushort*)d_ws;
  size_t off = 0;
  auto alloc = [&](size_t nelem) { ushort* p = wsu + off; off += (nelem + 7) & ~7ull; return p; };
  ushort* inW1t = alloc((size_t)DFF * DIN);
  ushort* inW2t = alloc((size_t)DD * DFF);
  ushort* Wqkvt = alloc((size_t)NL * 3 * DD * DD);
  ushort* Wot   = alloc((size_t)NL * DD * DD);
  ushort* W1t   = alloc((size_t)NL * DFF * DD);
  ushort* W2t   = alloc((size_t)NL * DD * DFF);
  ushort* x     = alloc((size_t)RROWS * DIN);
  ushort* tq    = alloc((size_t)RROWS * 3 * DD);
  ushort* hb    = alloc((size_t)RROWS * DD);
  ushort* ob    = alloc((size_t)RROWS * DD);
  float*  kp    = (float*)(wsu + off);

  int L = out_size / (BB * DD);                      // 160

  TPack tp;
  tp.d[0] = {in_W1, inW1t, DIN, DFF};
  tp.d[1] = {in_W2, inW2t, DFF, DD};
  tp.d[2] = {Wqkv,                        Wqkvt,                       DD, 3 * DD};
  tp.d[3] = {Wqkv + (size_t)DD * 3 * DD,  Wqkvt + (size_t)3 * DD * DD, DD, 3 * DD};
  tp.d[4] = {Wo,                    Wot,                   DD, DD};
  tp.d[5] = {Wo + (size_t)DD * DD,  Wot + (size_t)DD * DD, DD, DD};
  tp.d[6] = {W1,                      W1t,                    DD, DFF};
  tp.d[7] = {W1 + (size_t)DD * DFF,   W1t + (size_t)DFF * DD, DD, DFF};
  tp.d[8] = {W2,                      W2t,                    DFF, DD};
  tp.d[9] = {W2 + (size_t)DFF * DD,   W2t + (size_t)DD * DFF, DFF, DD};

  k_prep<<<WCONV_TILES + BX_BLOCKS + NN * BB, 256, 0, stream>>>(
      tp, inputs, x, k_W1, k_b1, k_W2, k_b2, kp);

  k_inmlp<<<RROWS / 64, 512, 0, stream>>>(x, inW1t, in_b1, inW2t, in_b2, hb);

  for (int l = 0; l < NL; ++l) {
    k_gemm8<128><<<dim3(RROWS / 128, 3), 512, 0, stream>>>(
        hb, Wqkvt + (size_t)l * 3 * DD * DD, bqkv + (size_t)l * 3 * DD,
        tq, 3 * DD, DD);
    k_attn<<<NN * BB * NH, 320, 0, stream>>>(tq, ob, lenp);
    k_layer<<<RROWS / 64, 512, 0, stream>>>(
        ob, Wot + (size_t)l * DD * DD, bo + (size_t)l * DD,
        ln1_g + (size_t)l * DD, ln1_b + (size_t)l * DD,
        W1t + (size_t)l * DFF * DD, b1 + (size_t)l * DFF,
        W2t + (size_t)l * DD * DFF, b2 + (size_t)l * DD,
        ln2_g + (size_t)l * DD, ln2_b + (size_t)l * DD, hb);
  }
  k_final<<<L * BB, 256, 0, stream>>>(hb, kp, out, lenp);
}